// Round 8
// baseline (409.851 us; speedup 1.0000x reference)
//
#include <hip/hip_runtime.h>

#define NN 256
#define XD 256
#define ED 128

typedef __attribute__((ext_vector_type(8))) short short8;
typedef __attribute__((ext_vector_type(4))) float f32x4;
typedef __attribute__((ext_vector_type(2))) unsigned int uint2v;

__device__ __forceinline__ unsigned short f2bf(float f) {
    unsigned u = __builtin_bit_cast(unsigned, f);
    u += 0x7FFF + ((u >> 16) & 1);
    return (unsigned short)(u >> 16);
}

// native packed f32->bf16 (RNE), 1 instr per 2 floats
__device__ __forceinline__ unsigned cvtpk(float lo, float hi) {
    unsigned r;
    asm("v_cvt_pk_bf16_f32 %0, %1, %2" : "=v"(r) : "v"(lo), "v"(hi));
    return r;
}

#define MFMA16(a, b, c) __builtin_amdgcn_mfma_f32_16x16x32_bf16(a, b, c, 0, 0, 0)

// ---------------------------------------------------------------------------
// Weight prep: transpose + bf16-convert all 7 weights to [n][k] layout.
// ---------------------------------------------------------------------------
__global__ __launch_bounds__(256) void wprep_kernel(
    const float* __restrict__ Wq, const float* __restrict__ Wk,
    const float* __restrict__ Wv, const float* __restrict__ Wxo,
    const float* __restrict__ Wem, const float* __restrict__ Wea,
    const float* __restrict__ Weo,
    short* __restrict__ WqT, short* __restrict__ WkT,
    short* __restrict__ WvT, short* __restrict__ WxoT,
    short* __restrict__ WemT, short* __restrict__ WeaT,
    short* __restrict__ WeoT)
{
    __shared__ float sT[32][33];
    int blk = blockIdx.x;
    const float* src; short* dst; int din, dout, tile;
    if (blk < 256) {
        int m = blk >> 6; tile = blk & 63; din = 256; dout = 256;
        src = m == 0 ? Wq : (m == 1 ? Wk : (m == 2 ? Wv : Wxo));
        dst = m == 0 ? WqT : (m == 1 ? WkT : (m == 2 ? WvT : WxoT));
    } else if (blk < 320) {
        int m = (blk - 256) >> 5; tile = (blk - 256) & 31; din = 128; dout = 256;
        src = m == 0 ? Wem : Wea; dst = m == 0 ? WemT : WeaT;
    } else {
        tile = blk - 320; din = 256; dout = 128;
        src = Weo; dst = WeoT;
    }
    int ksh = (din == 256) ? 3 : 2;
    int kt = tile & ((1 << ksh) - 1);
    int nt = tile >> ksh;
    int c = threadIdx.x & 31, rbase = threadIdx.x >> 5;
    #pragma unroll
    for (int p = 0; p < 4; ++p) {
        int r = rbase + p * 8;
        sT[r][c] = src[(kt * 32 + r) * dout + nt * 32 + c];
    }
    __syncthreads();
    #pragma unroll
    for (int p = 0; p < 4; ++p) {
        int r = rbase + p * 8;
        dst[(nt * 32 + r) * din + kt * 32 + c] = (short)f2bf(sT[c][r]);
    }
}

// ---------------------------------------------------------------------------
// Q/K projection via MFMA. grid = 16 m-tiles (64 rows) x 2 mats = 32 blocks.
// Q row-major fp32 pre-scaled by 1/sqrt(32); K stored transposed KT[b][c][j].
// ---------------------------------------------------------------------------
__global__ __launch_bounds__(512) void proj_qk_kernel(
    const float* __restrict__ x, const short* __restrict__ WqT,
    const short* __restrict__ WkT, const float* __restrict__ bq,
    const float* __restrict__ bk, float* __restrict__ Qs,
    float* __restrict__ KT)
{
    __shared__ unsigned short sX[64 * 264];
    const int blk = blockIdx.x;
    const int mtile = blk >> 1;   // 0..15 (64-row tile of the 1024 rows)
    const int mat   = blk & 1;    // 0: Q, 1: K
    const int tid = threadIdx.x, wave = tid >> 6, lane = tid & 63;
    const int quad = lane >> 4, l16 = lane & 15;

    {   // stage x tile fp32 -> bf16
        const float4* src4 = (const float4*)(x + (size_t)mtile * 64 * XD);
        #pragma unroll
        for (int it = 0; it < 8; ++it) {
            int idx4 = tid + it * 512;
            float4 v = src4[idx4];
            int elem = idx4 * 4, row = elem >> 8, col = elem & 255;
            short4 p = make_short4((short)f2bf(v.x), (short)f2bf(v.y),
                                   (short)f2bf(v.z), (short)f2bf(v.w));
            *(short4*)&sX[row * 264 + col] = p;
        }
    }
    __syncthreads();

    const short* WT   = mat ? WkT : WqT;
    const float* bias = mat ? bk : bq;
    const int c0 = wave * 32;

    f32x4 acc[4][2] = {};
    for (int ks = 0; ks < 8; ++ks) {
        short8 bfrag[2];
        #pragma unroll
        for (int ct = 0; ct < 2; ++ct)
            bfrag[ct] = *(const short8*)&WT[(c0 + ct * 16 + l16) * 256 + ks * 32 + quad * 8];
        #pragma unroll
        for (int mt = 0; mt < 4; ++mt) {
            short8 a = *(const short8*)&sX[(mt * 16 + l16) * 264 + ks * 32 + quad * 8];
            acc[mt][0] = MFMA16(a, bfrag[0], acc[mt][0]);
            acc[mt][1] = MFMA16(a, bfrag[1], acc[mt][1]);
        }
    }

    if (mat == 0) {
        #pragma unroll
        for (int mt = 0; mt < 4; ++mt)
            #pragma unroll
            for (int ct = 0; ct < 2; ++ct) {
                int cc = c0 + ct * 16 + l16;
                float bb = bias[cc];
                #pragma unroll
                for (int r = 0; r < 4; ++r)
                    Qs[(size_t)(mtile * 64 + mt * 16 + quad * 4 + r) * 256 + cc] =
                        (acc[mt][ct][r] + bb) * 0.17677669529663687f;
            }
    } else {
        int b = mtile >> 2, j0p = (mtile & 3) * 64;
        #pragma unroll
        for (int mt = 0; mt < 4; ++mt)
            #pragma unroll
            for (int ct = 0; ct < 2; ++ct) {
                int cc = c0 + ct * 16 + l16;
                float bb = bias[cc];
                f32x4 st;
                #pragma unroll
                for (int r = 0; r < 4; ++r) st[r] = acc[mt][ct][r] + bb;
                *(f32x4*)&KT[(size_t)(b * 256 + cc) * 256 + j0p + mt * 16 + quad * 4] = st;
            }
    }
}

// ---------------------------------------------------------------------------
// V = x@Wv + bv (bf16 in LDS), then newX = V@Wxo + bxo.
// grid = 16 m-tiles (64 rows), 512 threads.
// ---------------------------------------------------------------------------
__global__ __launch_bounds__(512) void proj_vx_kernel(
    const float* __restrict__ x, const short* __restrict__ WvT,
    const float* __restrict__ bv, const short* __restrict__ WxoT,
    const float* __restrict__ bxo, float* __restrict__ outX)
{
    __shared__ unsigned short sX[64 * 264];
    __shared__ unsigned short sV[64 * 264];
    const int mtile = blockIdx.x;
    const int tid = threadIdx.x, wave = tid >> 6, lane = tid & 63;
    const int quad = lane >> 4, l16 = lane & 15;

    {
        const float4* src4 = (const float4*)(x + (size_t)mtile * 64 * XD);
        #pragma unroll
        for (int it = 0; it < 8; ++it) {
            int idx4 = tid + it * 512;
            float4 v = src4[idx4];
            int elem = idx4 * 4, row = elem >> 8, col = elem & 255;
            short4 p = make_short4((short)f2bf(v.x), (short)f2bf(v.y),
                                   (short)f2bf(v.z), (short)f2bf(v.w));
            *(short4*)&sX[row * 264 + col] = p;
        }
    }
    __syncthreads();

    const int c0 = wave * 32;
    f32x4 acc[4][2] = {};
    for (int ks = 0; ks < 8; ++ks) {
        short8 bfrag[2];
        #pragma unroll
        for (int ct = 0; ct < 2; ++ct)
            bfrag[ct] = *(const short8*)&WvT[(c0 + ct * 16 + l16) * 256 + ks * 32 + quad * 8];
        #pragma unroll
        for (int mt = 0; mt < 4; ++mt) {
            short8 a = *(const short8*)&sX[(mt * 16 + l16) * 264 + ks * 32 + quad * 8];
            acc[mt][0] = MFMA16(a, bfrag[0], acc[mt][0]);
            acc[mt][1] = MFMA16(a, bfrag[1], acc[mt][1]);
        }
    }
    #pragma unroll
    for (int mt = 0; mt < 4; ++mt)
        #pragma unroll
        for (int ct = 0; ct < 2; ++ct) {
            int cc = c0 + ct * 16 + l16;
            float bb = bv[cc];
            #pragma unroll
            for (int r = 0; r < 4; ++r)
                sV[(mt * 16 + quad * 4 + r) * 264 + cc] = f2bf(acc[mt][ct][r] + bb);
        }
    __syncthreads();

    f32x4 acc2[4][2] = {};
    for (int ks = 0; ks < 8; ++ks) {
        short8 bfrag[2];
        #pragma unroll
        for (int ct = 0; ct < 2; ++ct)
            bfrag[ct] = *(const short8*)&WxoT[(c0 + ct * 16 + l16) * 256 + ks * 32 + quad * 8];
        #pragma unroll
        for (int mt = 0; mt < 4; ++mt) {
            short8 a = *(const short8*)&sV[(mt * 16 + l16) * 264 + ks * 32 + quad * 8];
            acc2[mt][0] = MFMA16(a, bfrag[0], acc2[mt][0]);
            acc2[mt][1] = MFMA16(a, bfrag[1], acc2[mt][1]);
        }
    }
    #pragma unroll
    for (int mt = 0; mt < 4; ++mt)
        #pragma unroll
        for (int ct = 0; ct < 2; ++ct) {
            int cc = c0 + ct * 16 + l16;
            float bb = bxo[cc];
            #pragma unroll
            for (int r = 0; r < 4; ++r)
                outX[(size_t)(mtile * 64 + mt * 16 + quad * 4 + r) * 256 + cc] =
                    acc2[mt][ct][r] + bb;
        }
}

// ---------------------------------------------------------------------------
// Fused edge kernel v11 = v10 (158.2us) +
//  - BOTH-pass kv/Q/bias prefetch at block top, pre-barrier: their latency
//    merges into the stage drain (1 exposure/block instead of 1/pass).
//  - cvt_pk for stage + sY converts (v5-validated: halves convert VALU).
//  - GEMM2 repartition (o-half x j-half; lifted from v6 which PASSED):
//    sY reads 32->16 ds_read_b128, stores 32 scalar -> 8 dwordx4 nt.
//  - kept: nt e-loads, nt stores, setprio, pre-barrier B3(ks0,1) prefetch.
// ---------------------------------------------------------------------------
__global__ __launch_bounds__(256, 3) void fused_edge_kernel(
    const float* __restrict__ e, const float* __restrict__ Qs,
    const float* __restrict__ KT, const short* __restrict__ WemT,
    const short* __restrict__ WeaT, const short* __restrict__ WeoT,
    const float* __restrict__ bem, const float* __restrict__ bea,
    const float* __restrict__ beo, float* __restrict__ outE)
{
    __shared__ unsigned short sE[64 * 140];   // e tile bf16, pitch 140
    __shared__ unsigned short sY[64 * 268];   // Y tile bf16, pitch 268

    const int blk  = blockIdx.x;              // 4096 blocks
    const int jq   = blk & 3;
    const int i    = (blk >> 2) & 255;
    const int b    = blk >> 10;
    const int j0   = jq * 64;
    const int tid  = threadIdx.x;
    const int wave = tid >> 6;
    const int lane = tid & 63;
    const int quad = lane >> 4;
    const int l16  = lane & 15;

    // ---- stage e tile [64 x 128] fp32 -> bf16 LDS (nt loads, cvt_pk)
    {
        const f32x4* src4 = (const f32x4*)(e + (size_t)((b * NN + i) * NN + j0) * ED);
        #pragma unroll
        for (int it = 0; it < 8; ++it) {
            int idx4 = tid + it * 256;
            f32x4 v = __builtin_nontemporal_load(&src4[idx4]);
            int elem = idx4 * 4, row = elem >> 7, col = elem & 127;
            uint2v p; p.x = cvtpk(v[0], v[1]); p.y = cvtpk(v[2], v[3]);
            *(uint2v*)&sE[row * 140 + col] = p;
        }
    }

    // ---- both-pass scalars + kv prefetch (pre-barrier: latency merges with
    //      the stage drain; no LDS dependence)
    const float* Qrow = Qs + (size_t)(b * NN + i) * XD;
    float qsv[2][2], bmv[2][2], bav[2][2];
    int ktA[2][2];
    #pragma unroll
    for (int p = 0; p < 2; ++p)
        #pragma unroll
        for (int ct = 0; ct < 2; ++ct) {
            int cc = wave * 32 + p * 128 + ct * 16 + l16;
            qsv[p][ct] = Qrow[cc];
            bmv[p][ct] = bem[cc] + 1.0f;
            bav[p][ct] = bea[cc];
            ktA[p][ct] = (b * 256 + cc) * 256 + j0 + quad * 4;
        }
    f32x4 kvp[2][4][2];
    #pragma unroll
    for (int p = 0; p < 2; ++p)
        #pragma unroll
        for (int mc = 0; mc < 4; ++mc)
            #pragma unroll
            for (int ct = 0; ct < 2; ++ct)
                kvp[p][mc][ct] = *(const f32x4*)&KT[ktA[p][ct] + mc * 16];

    __syncthreads();

    // ---- GEMM1 + combine, pass-outer over column halves
    #pragma unroll
    for (int p = 0; p < 2; ++p) {
        const int c0 = wave * 32 + p * 128;
        // register-resident B fragments for this pass (reused by all 4 m-chunks)
        short8 B1[4][2], B2[4][2];
        #pragma unroll
        for (int ks = 0; ks < 4; ++ks)
            #pragma unroll
            for (int ct = 0; ct < 2; ++ct) {
                int n = c0 + ct * 16 + l16;
                B1[ks][ct] = *(const short8*)&WemT[n * 128 + ks * 32 + quad * 8];
                B2[ks][ct] = *(const short8*)&WeaT[n * 128 + ks * 32 + quad * 8];
            }
        #pragma unroll
        for (int mc = 0; mc < 4; ++mc) {
            const int m0 = mc * 16;
            f32x4 aE1[2] = {}, aE2[2] = {};
            __builtin_amdgcn_s_setprio(1);
            #pragma unroll
            for (int ks = 0; ks < 4; ++ks) {
                short8 a = *(const short8*)&sE[(m0 + l16) * 140 + ks * 32 + quad * 8];
                aE1[0] = MFMA16(a, B1[ks][0], aE1[0]);
                aE1[1] = MFMA16(a, B1[ks][1], aE1[1]);
                aE2[0] = MFMA16(a, B2[ks][0], aE2[0]);
                aE2[1] = MFMA16(a, B2[ks][1], aE2[1]);
            }
            __builtin_amdgcn_s_setprio(0);
            #pragma unroll
            for (int ct = 0; ct < 2; ++ct) {
                int cc = c0 + ct * 16 + l16;
                float y0 = qsv[p][ct] * kvp[p][mc][ct][0] * (aE1[ct][0] + bmv[p][ct]) + (aE2[ct][0] + bav[p][ct]);
                float y1 = qsv[p][ct] * kvp[p][mc][ct][1] * (aE1[ct][1] + bmv[p][ct]) + (aE2[ct][1] + bav[p][ct]);
                float y2 = qsv[p][ct] * kvp[p][mc][ct][2] * (aE1[ct][2] + bmv[p][ct]) + (aE2[ct][2] + bav[p][ct]);
                float y3 = qsv[p][ct] * kvp[p][mc][ct][3] * (aE1[ct][3] + bmv[p][ct]) + (aE2[ct][3] + bav[p][ct]);
                unsigned u01 = cvtpk(y0, y1), u23 = cvtpk(y2, y3);
                int rb = (m0 + quad * 4) * 268 + cc;
                sY[rb]           = (unsigned short)u01;
                sY[rb + 268]     = (unsigned short)(u01 >> 16);
                sY[rb + 2 * 268] = (unsigned short)u23;
                sY[rb + 3 * 268] = (unsigned short)(u23 >> 16);
            }
        }
    }

    // ---- GEMM2 prefetch (pre-barrier: drained by barrier while others compute)
    const int oH = (wave & 1) * 64;           // o-half
    const int jH = (wave >> 1) * 2;           // j-half (2 jt tiles of 16 rows)
    short8 w01[2][4];
    #pragma unroll
    for (int ks = 0; ks < 2; ++ks)
        #pragma unroll
        for (int oT = 0; oT < 4; ++oT)
            w01[ks][oT] = *(const short8*)&WeoT[(oH + oT * 16 + l16) * 256 + ks * 32 + quad * 8];
    f32x4 bo4[4];
    #pragma unroll
    for (int oT = 0; oT < 4; ++oT)
        bo4[oT] = *(const f32x4*)&beo[oH + oT * 16 + quad * 4];
    __syncthreads();

    // ---- GEMM2 (repartitioned, v6-validated): wave = (o-half, j-half)
    f32x4 acc[4][2] = {};
    #pragma unroll
    for (int ks = 0; ks < 8; ++ks) {
        short8 wo[4];
        if (ks < 2) {
            #pragma unroll
            for (int oT = 0; oT < 4; ++oT) wo[oT] = w01[ks][oT];
        } else {
            #pragma unroll
            for (int oT = 0; oT < 4; ++oT)
                wo[oT] = *(const short8*)&WeoT[(oH + oT * 16 + l16) * 256 + ks * 32 + quad * 8];
        }
        __builtin_amdgcn_s_setprio(1);
        #pragma unroll
        for (int jt = 0; jt < 2; ++jt) {
            short8 yb = *(const short8*)&sY[((jH + jt) * 16 + l16) * 268 + ks * 32 + quad * 8];
            #pragma unroll
            for (int oT = 0; oT < 4; ++oT)
                acc[oT][jt] = MFMA16(wo[oT], yb, acc[oT][jt]);
        }
        __builtin_amdgcn_s_setprio(0);
    }

    // ---- store newE (nt, dwordx4)
    float* outBase = outE + (size_t)((b * NN + i) * NN + j0) * ED;
    #pragma unroll
    for (int oT = 0; oT < 4; ++oT) {
        const int oq = oH + oT * 16 + quad * 4;
        #pragma unroll
        for (int jt = 0; jt < 2; ++jt) {
            f32x4 st = acc[oT][jt] + bo4[oT];
            __builtin_nontemporal_store(st,
                (f32x4*)&outBase[(size_t)((jH + jt) * 16 + l16) * ED + oq]);
        }
    }
}

extern "C" void kernel_launch(void* const* d_in, const int* in_sizes, int n_in,
                              void* d_out, int out_size, void* d_ws, size_t ws_size,
                              hipStream_t stream)
{
    const float* x   = (const float*)d_in[0];
    const float* e   = (const float*)d_in[1];
    const float* Wq  = (const float*)d_in[2];
    const float* bq  = (const float*)d_in[3];
    const float* Wk  = (const float*)d_in[4];
    const float* bk  = (const float*)d_in[5];
    const float* Wv  = (const float*)d_in[6];
    const float* bv  = (const float*)d_in[7];
    const float* Wem = (const float*)d_in[8];
    const float* bem = (const float*)d_in[9];
    const float* Wea = (const float*)d_in[10];
    const float* bea = (const float*)d_in[11];
    const float* Wxo = (const float*)d_in[12];
    const float* bxo = (const float*)d_in[13];
    const float* Weo = (const float*)d_in[14];
    const float* beo = (const float*)d_in[15];

    float* outX = (float*)d_out;                 // newX: 262144 f32
    float* outE = (float*)d_out + 262144;        // newE: 33554432 f32

    float* Qs   = (float*)d_ws;                  // [1024][256] f32 (scaled)
    float* KT   = Qs + 262144;                   // [4][256 c][256 j] f32
    short* WqT  = (short*)(KT + 262144);         // [256][256] bf16
    short* WkT  = WqT + 65536;
    short* WvT  = WkT + 65536;
    short* WxoT = WvT + 65536;
    short* WemT = WxoT + 65536;                  // [256][128] bf16
    short* WeaT = WemT + 32768;
    short* WeoT = WeaT + 32768;                  // [128][256] bf16

    hipLaunchKernelGGL(wprep_kernel, dim3(352), dim3(256), 0, stream,
                       Wq, Wk, Wv, Wxo, Wem, Wea, Weo,
                       WqT, WkT, WvT, WxoT, WemT, WeaT, WeoT);
    hipLaunchKernelGGL(proj_qk_kernel, dim3(32), dim3(512), 0, stream,
                       x, WqT, WkT, bq, bk, Qs, KT);
    hipLaunchKernelGGL(proj_vx_kernel, dim3(16), dim3(512), 0, stream,
                       x, WvT, bv, WxoT, bxo, outX);
    hipLaunchKernelGGL(fused_edge_kernel, dim3(4096), dim3(256), 0, stream,
                       e, Qs, KT, WemT, WeaT, WeoT, bem, bea, beo, outE);
}